// Round 1
// baseline (8997.088 us; speedup 1.0000x reference)
//
#include <hip/hip_runtime.h>

#define H    512
#define DOBS 256
#define BATCH 32
#define SEQ  2048

typedef float f8 __attribute__((ext_vector_type(8)));

// ---------------- C[M][N] = A[M][K] @ B[N][K]^T + bias[N] ----------------
__global__ __launch_bounds__(256) void gemm_bias_k(const float* __restrict__ A,
                                                   const float* __restrict__ B,
                                                   const float* __restrict__ bias,
                                                   float* __restrict__ C,
                                                   int M, int N, int K) {
  __shared__ float As[32][68];
  __shared__ float Bs[32][68];
  const int m0 = blockIdx.x * 64;
  const int n0 = blockIdx.y * 64;
  const int t  = threadIdx.x;
  const int tm = (t >> 4) * 4;
  const int tn = (t & 15) * 4;
  const int lrow = t >> 3;
  const int lcol = (t & 7) * 4;

  float acc[4][4] = {};

  for (int k0 = 0; k0 < K; k0 += 32) {
    float4 a0 = *(const float4*)&A[(size_t)(m0 + lrow)      * K + k0 + lcol];
    float4 a1 = *(const float4*)&A[(size_t)(m0 + lrow + 32) * K + k0 + lcol];
    float4 b0 = *(const float4*)&B[(size_t)(n0 + lrow)      * K + k0 + lcol];
    float4 b1 = *(const float4*)&B[(size_t)(n0 + lrow + 32) * K + k0 + lcol];
    __syncthreads();
    As[lcol + 0][lrow] = a0.x; As[lcol + 1][lrow] = a0.y;
    As[lcol + 2][lrow] = a0.z; As[lcol + 3][lrow] = a0.w;
    As[lcol + 0][lrow + 32] = a1.x; As[lcol + 1][lrow + 32] = a1.y;
    As[lcol + 2][lrow + 32] = a1.z; As[lcol + 3][lrow + 32] = a1.w;
    Bs[lcol + 0][lrow] = b0.x; Bs[lcol + 1][lrow] = b0.y;
    Bs[lcol + 2][lrow] = b0.z; Bs[lcol + 3][lrow] = b0.w;
    Bs[lcol + 0][lrow + 32] = b1.x; Bs[lcol + 1][lrow + 32] = b1.y;
    Bs[lcol + 2][lrow + 32] = b1.z; Bs[lcol + 3][lrow + 32] = b1.w;
    __syncthreads();
#pragma unroll
    for (int k = 0; k < 32; ++k) {
      float4 a = *(const float4*)&As[k][tm];
      float4 b = *(const float4*)&Bs[k][tn];
      acc[0][0] = fmaf(a.x, b.x, acc[0][0]);
      acc[0][1] = fmaf(a.x, b.y, acc[0][1]);
      acc[0][2] = fmaf(a.x, b.z, acc[0][2]);
      acc[0][3] = fmaf(a.x, b.w, acc[0][3]);
      acc[1][0] = fmaf(a.y, b.x, acc[1][0]);
      acc[1][1] = fmaf(a.y, b.y, acc[1][1]);
      acc[1][2] = fmaf(a.y, b.z, acc[1][2]);
      acc[1][3] = fmaf(a.y, b.w, acc[1][3]);
      acc[2][0] = fmaf(a.z, b.x, acc[2][0]);
      acc[2][1] = fmaf(a.z, b.y, acc[2][1]);
      acc[2][2] = fmaf(a.z, b.z, acc[2][2]);
      acc[2][3] = fmaf(a.z, b.w, acc[2][3]);
      acc[3][0] = fmaf(a.w, b.x, acc[3][0]);
      acc[3][1] = fmaf(a.w, b.y, acc[3][1]);
      acc[3][2] = fmaf(a.w, b.z, acc[3][2]);
      acc[3][3] = fmaf(a.w, b.w, acc[3][3]);
    }
  }

  float4 b4 = *(const float4*)&bias[n0 + tn];
#pragma unroll
  for (int i = 0; i < 4; ++i) {
    float4 c;
    c.x = acc[i][0] + b4.x;
    c.y = acc[i][1] + b4.y;
    c.z = acc[i][2] + b4.z;
    c.w = acc[i][3] + b4.w;
    *(float4*)&C[(size_t)(m0 + tm + i) * N + n0 + tn] = c;
  }
}

// ---------------- recurrence: 32 chains x 32 autonomous waves -------------
// Each wave owns 16 outputs end-to-end: 4 lanes per output, each lane covers a
// 128-wide k-chunk with weights in VGPRs (f8 Wv[16] = 128 VGPRs, row-major
// from Whh_w -> no transpose needed). No __syncthreads anywhere: the partial
// reduction is 2x shfl_xor within the 4-lane group. Communication protocol as
// before: owners publish h+1 into exch (>= 1.0 == ready), clean h to hid.
// New: (1) each step issues a discarded agent-load of eb[t] so the line's HBM
// fill happens UNDER this step's compute and the t+1 poll hits L2-dirty;
// (2) xp is prefetched one full step ahead.
__global__ __launch_bounds__(256, 1) void rnn_rec_k(float* __restrict__ hid,
                                                    float* __restrict__ exch,
                                                    const float* __restrict__ W,
                                                    const float* __restrict__ bias) {
  const int b    = blockIdx.x & (BATCH - 1);   // spacing 32 keeps a chain on one XCD
  const int sgrp = blockIdx.x >> 5;            // 0..7
  const int tid  = threadIdx.x;
  const int w    = tid >> 6;                   // wave 0..3 (independent units)
  const int l    = tid & 63;
  const int c    = l & 3;                      // k-chunk 0..3 (128 wide)
  const int oo   = l >> 2;                     // output 0..15 within wave
  const int nout = sgrp * 64 + w * 16 + oo;    // this 4-lane group's output col
  const bool lead = (c == 0);

  // per-wave h buffer, chunk stride 132 words: groups c=0..3 read banks
  // 4c+8i..+7 -> disjoint mod 32, 16-lane same-address broadcast -> conflict-free
  __shared__ __align__(16) float shh[4][4 * 132];

  float* hb = hid  + (size_t)b * SEQ * H;
  float* eb = exch + (size_t)b * SEQ * H;

  // one-time weight preload, row-major: Wv[i][j] = W[nout][c*128 + 8i + j]
  f8 Wv[16];
  {
    const float* wp = W + (size_t)nout * H + c * 128;
#pragma unroll
    for (int i = 0; i < 16; ++i) Wv[i] = *(const f8*)(wp + 8 * i);
  }
  const float bn = bias[nout];

  float* shw = shh[w];
  float* swr = shw + 8 * l + ((l >> 4) << 2);  // lane's 8-float write slot (padded)
  const float* srd = shw + c * 132;            // lane's read base (its k-chunk)

  float xp_next = lead ? hb[nout] : 0.f;       // xp for t=0

  for (int t = 0; t < SEQ; ++t) {
    const float xp = xp_next;
    {  // prefetch xp(t+1) a full step early
      const int tn = (t + 1 < SEQ) ? t + 1 : t;
      if (lead) xp_next = hb[(size_t)tn * H + nout];
    }
    // L2-prefetch this step's exchange row (polled at t+1); value discarded.
    float pfv = __hip_atomic_load(eb + (size_t)t * H + 8 * l,
                                  __ATOMIC_RELAXED, __HIP_MEMORY_SCOPE_AGENT);

    float r = 0.f;
    if (t > 0) {
      float* ep = eb + (size_t)(t - 1) * H + 8 * l;
      float v0, v1, v2, v3, v4, v5, v6, v7;
      for (;;) {
        v0 = __hip_atomic_load(ep + 0, __ATOMIC_RELAXED, __HIP_MEMORY_SCOPE_AGENT);
        v1 = __hip_atomic_load(ep + 1, __ATOMIC_RELAXED, __HIP_MEMORY_SCOPE_AGENT);
        v2 = __hip_atomic_load(ep + 2, __ATOMIC_RELAXED, __HIP_MEMORY_SCOPE_AGENT);
        v3 = __hip_atomic_load(ep + 3, __ATOMIC_RELAXED, __HIP_MEMORY_SCOPE_AGENT);
        v4 = __hip_atomic_load(ep + 4, __ATOMIC_RELAXED, __HIP_MEMORY_SCOPE_AGENT);
        v5 = __hip_atomic_load(ep + 5, __ATOMIC_RELAXED, __HIP_MEMORY_SCOPE_AGENT);
        v6 = __hip_atomic_load(ep + 6, __ATOMIC_RELAXED, __HIP_MEMORY_SCOPE_AGENT);
        v7 = __hip_atomic_load(ep + 7, __ATOMIC_RELAXED, __HIP_MEMORY_SCOPE_AGENT);
        bool ok = (v0 >= 1.f) & (v1 >= 1.f) & (v2 >= 1.f) & (v3 >= 1.f) &
                  (v4 >= 1.f) & (v5 >= 1.f) & (v6 >= 1.f) & (v7 >= 1.f);
        if (!__any(!ok)) break;
      }
      // wave-local LDS broadcast (64 lanes cover all 512 values)
      float4 hA = {v0 - 1.f, v1 - 1.f, v2 - 1.f, v3 - 1.f};
      float4 hB = {v4 - 1.f, v5 - 1.f, v6 - 1.f, v7 - 1.f};
      *(float4*)swr = hA;
      *(float4*)(swr + 4) = hB;
      asm volatile("s_waitcnt lgkmcnt(0)" ::: "memory");

      float a0 = 0.f, a1 = 0.f, a2 = 0.f, a3 = 0.f;
#pragma unroll
      for (int i = 0; i < 16; ++i) {
        float4 x0 = *(const float4*)(srd + 8 * i);
        float4 x1 = *(const float4*)(srd + 8 * i + 4);
        a0 = fmaf(Wv[i][0], x0.x, a0);
        a1 = fmaf(Wv[i][1], x0.y, a1);
        a2 = fmaf(Wv[i][2], x0.z, a2);
        a3 = fmaf(Wv[i][3], x0.w, a3);
        a0 = fmaf(Wv[i][4], x1.x, a0);
        a1 = fmaf(Wv[i][5], x1.y, a1);
        a2 = fmaf(Wv[i][6], x1.z, a2);
        a3 = fmaf(Wv[i][7], x1.w, a3);
      }
      r = (a0 + a1) + (a2 + a3);
      // reduce the 4 k-chunk partials within the lane group
      r += __shfl_xor(r, 1, 64);
      r += __shfl_xor(r, 2, 64);
    }

    if (lead) {
      float hv = fmaxf(r + xp + bn, 0.f);
      // publish h+1 (self-flagging) for all peer waves
      __hip_atomic_store(&eb[(size_t)t * H + nout], hv + 1.0f,
                         __ATOMIC_RELAXED, __HIP_MEMORY_SCOPE_AGENT);
      // clean h for hidden_arr / next GEMM
      hb[(size_t)t * H + nout] = hv;
    }
    // keep the prefetch alive (rule: ablation-via-skip DCEs dead loads);
    // placed at iteration end so its waitcnt lands after the step's compute.
    asm volatile("" :: "v"(pfv));
  }
}

// ---------------- in-place row softmax over 512 cols ----------------
__global__ __launch_bounds__(256) void softmax_k(float* __restrict__ Z) {
  __shared__ float smax[4];
  __shared__ float ssum[4];
  float* row = Z + (size_t)blockIdx.x * H;
  const int t = threadIdx.x;
  float2 v = *(float2*)&row[2 * t];
  float m = fmaxf(v.x, v.y);
#pragma unroll
  for (int o = 32; o > 0; o >>= 1) m = fmaxf(m, __shfl_xor(m, o, 64));
  const int wave = t >> 6, lane = t & 63;
  if (lane == 0) smax[wave] = m;
  __syncthreads();
  m = fmaxf(fmaxf(smax[0], smax[1]), fmaxf(smax[2], smax[3]));
  const float LOG2E = 1.44269504088896f;
  float ex = exp2f((v.x - m) * LOG2E);
  float ey = exp2f((v.y - m) * LOG2E);
  float s = ex + ey;
#pragma unroll
  for (int o = 32; o > 0; o >>= 1) s += __shfl_xor(s, o, 64);
  if (lane == 0) ssum[wave] = s;
  __syncthreads();
  float inv = 1.0f / (ssum[0] + ssum[1] + ssum[2] + ssum[3]);
  float2 r;
  r.x = ex * inv;
  r.y = ey * inv;
  *(float2*)&row[2 * t] = r;
}

extern "C" void kernel_launch(void* const* d_in, const int* in_sizes, int n_in,
                              void* d_out, int out_size, void* d_ws, size_t ws_size,
                              hipStream_t stream) {
  const float* x     = (const float*)d_in[0];
  const float* Whx_w = (const float*)d_in[1];
  const float* Whx_b = (const float*)d_in[2];
  const float* Whh_w = (const float*)d_in[3];
  const float* Whh_b = (const float*)d_in[4];
  const float* Woh_w = (const float*)d_in[5];
  const float* Woh_b = (const float*)d_in[6];

  float* y   = (float*)d_out;                           // output_arr; doubles as h+1 exchange
  float* hid = (float*)d_out + (size_t)BATCH * SEQ * H; // hidden_arr: xp then h

  const int M = BATCH * SEQ;  // 65536

  gemm_bias_k<<<dim3(M / 64, H / 64), 256, 0, stream>>>(x, Whx_w, Whx_b, hid, M, H, DOBS);
  rnn_rec_k<<<BATCH * 8, 256, 0, stream>>>(hid, y, Whh_w, Whh_b);
  gemm_bias_k<<<dim3(M / 64, H / 64), 256, 0, stream>>>(hid, Woh_w, Woh_b, y, M, H, H);
  softmax_k<<<M, 256, 0, stream>>>(y);
}

// Round 2
// 3645.838 us; speedup vs baseline: 2.4678x; 2.4678x over previous
//
#include <hip/hip_runtime.h>

#define H    512
#define DOBS 256
#define BATCH 32
#define SEQ  2048
#define NSLICE 8   // WGs per chain
#define NS 64      // outputs per WG

typedef float f8 __attribute__((ext_vector_type(8)));

// ---------------- transpose 512x512: Wt[k][n] = W[n][k] ----------------
__global__ __launch_bounds__(256) void transpose_k(const float* __restrict__ W,
                                                   float* __restrict__ Wt) {
  __shared__ float tile[32][33];
  int tx  = threadIdx.x & 31;
  int ty4 = (threadIdx.x >> 5) * 4;
  int bx = blockIdx.x * 32;
  int by = blockIdx.y * 32;
#pragma unroll
  for (int i = 0; i < 4; ++i)
    tile[ty4 + i][tx] = W[(by + ty4 + i) * H + bx + tx];
  __syncthreads();
#pragma unroll
  for (int i = 0; i < 4; ++i)
    Wt[(bx + ty4 + i) * H + by + tx] = tile[tx][ty4 + i];
}

// ---------------- C[M][N] = A[M][K] @ B[N][K]^T + bias[N] ----------------
__global__ __launch_bounds__(256) void gemm_bias_k(const float* __restrict__ A,
                                                   const float* __restrict__ B,
                                                   const float* __restrict__ bias,
                                                   float* __restrict__ C,
                                                   int M, int N, int K) {
  __shared__ float As[32][68];
  __shared__ float Bs[32][68];
  const int m0 = blockIdx.x * 64;
  const int n0 = blockIdx.y * 64;
  const int t  = threadIdx.x;
  const int tm = (t >> 4) * 4;
  const int tn = (t & 15) * 4;
  const int lrow = t >> 3;
  const int lcol = (t & 7) * 4;

  float acc[4][4] = {};

  for (int k0 = 0; k0 < K; k0 += 32) {
    float4 a0 = *(const float4*)&A[(size_t)(m0 + lrow)      * K + k0 + lcol];
    float4 a1 = *(const float4*)&A[(size_t)(m0 + lrow + 32) * K + k0 + lcol];
    float4 b0 = *(const float4*)&B[(size_t)(n0 + lrow)      * K + k0 + lcol];
    float4 b1 = *(const float4*)&B[(size_t)(n0 + lrow + 32) * K + k0 + lcol];
    __syncthreads();
    As[lcol + 0][lrow] = a0.x; As[lcol + 1][lrow] = a0.y;
    As[lcol + 2][lrow] = a0.z; As[lcol + 3][lrow] = a0.w;
    As[lcol + 0][lrow + 32] = a1.x; As[lcol + 1][lrow + 32] = a1.y;
    As[lcol + 2][lrow + 32] = a1.z; As[lcol + 3][lrow + 32] = a1.w;
    Bs[lcol + 0][lrow] = b0.x; Bs[lcol + 1][lrow] = b0.y;
    Bs[lcol + 2][lrow] = b0.z; Bs[lcol + 3][lrow] = b0.w;
    Bs[lcol + 0][lrow + 32] = b1.x; Bs[lcol + 1][lrow + 32] = b1.y;
    Bs[lcol + 2][lrow + 32] = b1.z; Bs[lcol + 3][lrow + 32] = b1.w;
    __syncthreads();
#pragma unroll
    for (int k = 0; k < 32; ++k) {
      float4 a = *(const float4*)&As[k][tm];
      float4 b = *(const float4*)&Bs[k][tn];
      acc[0][0] = fmaf(a.x, b.x, acc[0][0]);
      acc[0][1] = fmaf(a.x, b.y, acc[0][1]);
      acc[0][2] = fmaf(a.x, b.z, acc[0][2]);
      acc[0][3] = fmaf(a.x, b.w, acc[0][3]);
      acc[1][0] = fmaf(a.y, b.x, acc[1][0]);
      acc[1][1] = fmaf(a.y, b.y, acc[1][1]);
      acc[1][2] = fmaf(a.y, b.z, acc[1][2]);
      acc[1][3] = fmaf(a.y, b.w, acc[1][3]);
      acc[2][0] = fmaf(a.z, b.x, acc[2][0]);
      acc[2][1] = fmaf(a.z, b.y, acc[2][1]);
      acc[2][2] = fmaf(a.z, b.z, acc[2][2]);
      acc[2][3] = fmaf(a.z, b.w, acc[2][3]);
      acc[3][0] = fmaf(a.w, b.x, acc[3][0]);
      acc[3][1] = fmaf(a.w, b.y, acc[3][1]);
      acc[3][2] = fmaf(a.w, b.z, acc[3][2]);
      acc[3][3] = fmaf(a.w, b.w, acc[3][3]);
    }
  }

  float4 b4 = *(const float4*)&bias[n0 + tn];
#pragma unroll
  for (int i = 0; i < 4; ++i) {
    float4 c;
    c.x = acc[i][0] + b4.x;
    c.y = acc[i][1] + b4.y;
    c.z = acc[i][2] + b4.z;
    c.w = acc[i][3] + b4.w;
    *(float4*)&C[(size_t)(m0 + tm + i) * N + n0 + tn] = c;
  }
}

// ---------------- recurrence: 32 chains x 8 slices ------------------------
// Round-0 verified structure (chunked polls, one barrier, wave0 finalize).
// Single change this round: each wave issues a PLAIN (non-atomic) prefetch
// load of its own 128-wide chunk of exch row t (the row it will poll at t+1).
// The load fills L3/MALL with the stale line UNDER this step's poll+FMA; the
// owner's agent store then updates the (now-resident) line, so the t+1 poll
// is an L3 hit instead of a ~900cy cold HBM miss. Keep-alive asm sits right
// BEFORE __syncthreads: the barrier's mandatory vmcnt(0) drain absorbs the
// fill latency (round-1's mistake was forcing the wait without the overlap).
// Polls are agent-scope (bypass L2), so the stale L2 copy is never read.
__global__ __launch_bounds__(256, 1) void rnn_rec_k(float* __restrict__ hid,
                                                    float* __restrict__ exch,
                                                    const float* __restrict__ Wt,
                                                    const float* __restrict__ bias) {
  const int b     = blockIdx.x & (BATCH - 1);
  const int slice = blockIdx.x >> 5;
  const int n0    = slice * NS;
  const int tid   = threadIdx.x;
  const int w     = tid >> 6;   // wave 0..3 -> k chunk of 128
  const int l     = tid & 63;

  __shared__ __align__(16) float shh[H];
  __shared__ float sh_part[2][4][NS];

  float* hb = hid  + (size_t)b * SEQ * H;
  float* eb = exch + (size_t)b * SEQ * H;

  // one-time weight preload into SSA vectors: Wv[i][j] = Wt[w*128+8i+j][n0+l]
  f8 Wv[16];
  {
    const float* wp = Wt + (size_t)(w * 128) * H + n0 + l;
#pragma unroll
    for (int i = 0; i < 16; ++i) {
#pragma unroll
      for (int j = 0; j < 8; ++j)
        Wv[i][j] = wp[(size_t)(i * 8 + j) * H];
    }
  }
  const float bn = bias[n0 + l];

  const float4* sh4 = (const float4*)&shh[w * 128];

  for (int t = 0; t < SEQ; ++t) {
    float xp = 0.f;
    if (w == 0) xp = hb[(size_t)t * H + n0 + l];  // prefetch xp_t

    // L3 prefetch of this step's exchange chunk (polled at t+1).
    // Plain loads: fills MALL; values consumed by keep-alive before barrier.
    const float* pf = eb + (size_t)t * H + w * 128;
    float p0 = pf[l];
    float p1 = pf[64 + l];

    float partial = 0.f;
    if (t > 0) {
      // poll this wave's 128-wide k-chunk of (h_{t-1}+1)
      const float* ep = eb + (size_t)(t - 1) * H + w * 128;
      float v0, v1;
      for (;;) {
        v0 = __hip_atomic_load(ep + l,      __ATOMIC_RELAXED, __HIP_MEMORY_SCOPE_AGENT);
        v1 = __hip_atomic_load(ep + 64 + l, __ATOMIC_RELAXED, __HIP_MEMORY_SCOPE_AGENT);
        if (!__any(!(v0 >= 1.0f && v1 >= 1.0f))) break;
      }
      // wave-local LDS broadcast (same wave produces & consumes its region)
      shh[w * 128 + l]      = v0 - 1.0f;
      shh[w * 128 + 64 + l] = v1 - 1.0f;
      asm volatile("s_waitcnt lgkmcnt(0)" ::: "memory");

      float a0 = 0.f, a1 = 0.f, a2 = 0.f, a3 = 0.f;
#pragma unroll
      for (int i = 0; i < 16; ++i) {
        float4 hA = sh4[2 * i];
        float4 hB = sh4[2 * i + 1];
        a0 = fmaf(Wv[i][0], hA.x, a0);
        a1 = fmaf(Wv[i][1], hA.y, a1);
        a2 = fmaf(Wv[i][2], hA.z, a2);
        a3 = fmaf(Wv[i][3], hA.w, a3);
        a0 = fmaf(Wv[i][4], hB.x, a0);
        a1 = fmaf(Wv[i][5], hB.y, a1);
        a2 = fmaf(Wv[i][6], hB.z, a2);
        a3 = fmaf(Wv[i][7], hB.w, a3);
      }
      partial = (a0 + a1) + (a2 + a3);
    }

    sh_part[t & 1][w][l] = partial;
    // keep prefetch alive; barrier's vmcnt(0) drain overlaps its fill with
    // the poll+FMA phase above (NOT a same-instant forced wait).
    asm volatile("" :: "v"(p0), "v"(p1));
    __syncthreads();  // one barrier per step; parity protects reuse

    if (w == 0) {
      float v = sh_part[t & 1][0][l] + sh_part[t & 1][1][l]
              + sh_part[t & 1][2][l] + sh_part[t & 1][3][l] + xp + bn;
      float hv = fmaxf(v, 0.f);
      // publish h+1 (self-flagging) for peers
      __hip_atomic_store(&eb[(size_t)t * H + n0 + l], hv + 1.0f,
                         __ATOMIC_RELAXED, __HIP_MEMORY_SCOPE_AGENT);
      // clean h for the output / next GEMM
      hb[(size_t)t * H + n0 + l] = hv;
    }
  }
}

// ---------------- in-place row softmax over 512 cols ----------------
__global__ __launch_bounds__(256) void softmax_k(float* __restrict__ Z) {
  __shared__ float smax[4];
  __shared__ float ssum[4];
  float* row = Z + (size_t)blockIdx.x * H;
  const int t = threadIdx.x;
  float2 v = *(float2*)&row[2 * t];
  float m = fmaxf(v.x, v.y);
#pragma unroll
  for (int o = 32; o > 0; o >>= 1) m = fmaxf(m, __shfl_xor(m, o, 64));
  const int wave = t >> 6, lane = t & 63;
  if (lane == 0) smax[wave] = m;
  __syncthreads();
  m = fmaxf(fmaxf(smax[0], smax[1]), fmaxf(smax[2], smax[3]));
  const float LOG2E = 1.44269504088896f;
  float ex = exp2f((v.x - m) * LOG2E);
  float ey = exp2f((v.y - m) * LOG2E);
  float s = ex + ey;
#pragma unroll
  for (int o = 32; o > 0; o >>= 1) s += __shfl_xor(s, o, 64);
  if (lane == 0) ssum[wave] = s;
  __syncthreads();
  float inv = 1.0f / (ssum[0] + ssum[1] + ssum[2] + ssum[3]);
  float2 r;
  r.x = ex * inv;
  r.y = ey * inv;
  *(float2*)&row[2 * t] = r;
}

extern "C" void kernel_launch(void* const* d_in, const int* in_sizes, int n_in,
                              void* d_out, int out_size, void* d_ws, size_t ws_size,
                              hipStream_t stream) {
  const float* x     = (const float*)d_in[0];
  const float* Whx_w = (const float*)d_in[1];
  const float* Whx_b = (const float*)d_in[2];
  const float* Whh_w = (const float*)d_in[3];
  const float* Whh_b = (const float*)d_in[4];
  const float* Woh_w = (const float*)d_in[5];
  const float* Woh_b = (const float*)d_in[6];

  float* y   = (float*)d_out;                           // output_arr; doubles as h+1 exchange
  float* hid = (float*)d_out + (size_t)BATCH * SEQ * H; // hidden_arr: xp then h
  float* Wt  = (float*)d_ws;                            // 1 MB

  const int M = BATCH * SEQ;  // 65536

  transpose_k<<<dim3(16, 16), 256, 0, stream>>>(Whh_w, Wt);
  gemm_bias_k<<<dim3(M / 64, H / 64), 256, 0, stream>>>(x, Whx_w, Whx_b, hid, M, H, DOBS);
  rnn_rec_k<<<BATCH * NSLICE, 256, 0, stream>>>(hid, y, Wt, Whh_b);
  gemm_bias_k<<<dim3(M / 64, H / 64), 256, 0, stream>>>(hid, Woh_w, Woh_b, y, M, H, H);
  softmax_k<<<M, 256, 0, stream>>>(y);
}

// Round 3
// 3577.322 us; speedup vs baseline: 2.5150x; 1.0192x over previous
//
#include <hip/hip_runtime.h>

#define H    512
#define DOBS 256
#define BATCH 32
#define SEQ  2048
#define NSLICE 8   // WGs per chain
#define NS 64      // outputs per WG

typedef float f8 __attribute__((ext_vector_type(8)));

// ---------------- transpose 512x512: Wt[k][n] = W[n][k] ----------------
__global__ __launch_bounds__(256) void transpose_k(const float* __restrict__ W,
                                                   float* __restrict__ Wt) {
  __shared__ float tile[32][33];
  int tx  = threadIdx.x & 31;
  int ty4 = (threadIdx.x >> 5) * 4;
  int bx = blockIdx.x * 32;
  int by = blockIdx.y * 32;
#pragma unroll
  for (int i = 0; i < 4; ++i)
    tile[ty4 + i][tx] = W[(by + ty4 + i) * H + bx + tx];
  __syncthreads();
#pragma unroll
  for (int i = 0; i < 4; ++i)
    Wt[(bx + ty4 + i) * H + by + tx] = tile[tx][ty4 + i];
}

// ---------------- C[M][N] = A[M][K] @ B[N][K]^T + bias[N] ----------------
// 128x128 tile, 8x8 accumulators: 4 ds_read_b128 per 64 FMA (was 2 per 16) —
// lifts the 4x4 version out of its LDS-read bound. A-reads broadcast (16
// lanes same addr); B-reads/writes are 2-way (free, m136). LDS 17 KB.
__global__ __launch_bounds__(256) void gemm_bias_k(const float* __restrict__ A,
                                                   const float* __restrict__ B,
                                                   const float* __restrict__ bias,
                                                   float* __restrict__ C,
                                                   int M, int N, int K) {
  __shared__ float As[16][132];
  __shared__ float Bs[16][132];
  const int m0 = blockIdx.x * 128;
  const int n0 = blockIdx.y * 128;
  const int t  = threadIdx.x;
  const int tm = (t >> 4) * 4;   // 0..60
  const int tn = (t & 15) * 4;   // 0..60
  const int lrow = t >> 2;       // 0..63
  const int lcol = (t & 3) * 4;  // 0,4,8,12

  float acc[8][8] = {};

  for (int k0 = 0; k0 < K; k0 += 16) {
    float4 a0 = *(const float4*)&A[(size_t)(m0 + lrow)      * K + k0 + lcol];
    float4 a1 = *(const float4*)&A[(size_t)(m0 + lrow + 64) * K + k0 + lcol];
    float4 b0 = *(const float4*)&B[(size_t)(n0 + lrow)      * K + k0 + lcol];
    float4 b1 = *(const float4*)&B[(size_t)(n0 + lrow + 64) * K + k0 + lcol];
    __syncthreads();
    As[lcol + 0][lrow] = a0.x; As[lcol + 1][lrow] = a0.y;
    As[lcol + 2][lrow] = a0.z; As[lcol + 3][lrow] = a0.w;
    As[lcol + 0][lrow + 64] = a1.x; As[lcol + 1][lrow + 64] = a1.y;
    As[lcol + 2][lrow + 64] = a1.z; As[lcol + 3][lrow + 64] = a1.w;
    Bs[lcol + 0][lrow] = b0.x; Bs[lcol + 1][lrow] = b0.y;
    Bs[lcol + 2][lrow] = b0.z; Bs[lcol + 3][lrow] = b0.w;
    Bs[lcol + 0][lrow + 64] = b1.x; Bs[lcol + 1][lrow + 64] = b1.y;
    Bs[lcol + 2][lrow + 64] = b1.z; Bs[lcol + 3][lrow + 64] = b1.w;
    __syncthreads();
#pragma unroll
    for (int k = 0; k < 16; ++k) {
      float4 aA = *(const float4*)&As[k][tm];
      float4 aB = *(const float4*)&As[k][tm + 64];
      float4 bA = *(const float4*)&Bs[k][tn];
      float4 bB = *(const float4*)&Bs[k][tn + 64];
      float av[8] = {aA.x, aA.y, aA.z, aA.w, aB.x, aB.y, aB.z, aB.w};
      float bv[8] = {bA.x, bA.y, bA.z, bA.w, bB.x, bB.y, bB.z, bB.w};
#pragma unroll
      for (int i = 0; i < 8; ++i)
#pragma unroll
        for (int j = 0; j < 8; ++j)
          acc[i][j] = fmaf(av[i], bv[j], acc[i][j]);
    }
  }

  float4 bbA = *(const float4*)&bias[n0 + tn];
  float4 bbB = *(const float4*)&bias[n0 + tn + 64];
#pragma unroll
  for (int i = 0; i < 8; ++i) {
    int row = m0 + ((i < 4) ? (tm + i) : (64 + tm + i - 4));
    float4 c0, c1;
    c0.x = acc[i][0] + bbA.x; c0.y = acc[i][1] + bbA.y;
    c0.z = acc[i][2] + bbA.z; c0.w = acc[i][3] + bbA.w;
    c1.x = acc[i][4] + bbB.x; c1.y = acc[i][5] + bbB.y;
    c1.z = acc[i][6] + bbB.z; c1.w = acc[i][7] + bbB.w;
    *(float4*)&C[(size_t)row * N + n0 + tn]      = c0;
    *(float4*)&C[(size_t)row * N + n0 + tn + 64] = c1;
  }
}

// ---------------- recurrence: 32 chains x 8 slices ------------------------
// Round-2 verified protocol (chunked agent polls, stale-line prefetch, one
// barrier, wave0 finalize). Round-3 scheduling changes, both driven by
// IN-ORDER vmem return (vmcnt semantics):
//  (1) poll loads are now the FIRST vmem ops of the step; prefetch + xp-load
//      issue AFTER the poll loop. Previously their HBM fills (~900cy) gated
//      the poll's first vmcnt(0) check even when the producer's store had
//      already landed (~250cy).
//  (2) __syncthreads (which drains vmcnt(0)) replaced by s_waitcnt lgkmcnt(0)
//      + raw s_barrier: the sh_part handshake needs LDS ordering only, so the
//      prefetch stays in flight across the barrier (counted-vmcnt idiom).
// Keep-alive for the carried prefetch sits right AFTER the poll loop, where
// vmcnt is already 0 -> zero-cost; its "memory" clobber pins prefetch issue
// below the poll against compiler hoisting.
__global__ __launch_bounds__(256, 1) void rnn_rec_k(float* __restrict__ hid,
                                                    float* __restrict__ exch,
                                                    const float* __restrict__ Wt,
                                                    const float* __restrict__ bias) {
  const int b     = blockIdx.x & (BATCH - 1);
  const int slice = blockIdx.x >> 5;
  const int n0    = slice * NS;
  const int tid   = threadIdx.x;
  const int w     = tid >> 6;   // wave 0..3 -> k chunk of 128
  const int l     = tid & 63;

  __shared__ __align__(16) float shh[H];
  __shared__ float sh_part[2][4][NS];

  float* hb = hid  + (size_t)b * SEQ * H;
  float* eb = exch + (size_t)b * SEQ * H;

  // one-time weight preload into SSA vectors: Wv[i][j] = Wt[w*128+8i+j][n0+l]
  f8 Wv[16];
  {
    const float* wp = Wt + (size_t)(w * 128) * H + n0 + l;
#pragma unroll
    for (int i = 0; i < 16; ++i) {
#pragma unroll
      for (int j = 0; j < 8; ++j)
        Wv[i][j] = wp[(size_t)(i * 8 + j) * H];
    }
  }
  const float bn = bias[n0 + l];

  const float4* sh4 = (const float4*)&shh[w * 128];

  float xp_cur = 0.f, xp_nxt = 0.f;
  if (w == 0) xp_cur = hb[n0 + l];  // xp row 0
  float kp0 = 0.f, kp1 = 0.f;       // carried prefetch values

  for (int t = 0; t < SEQ; ++t) {
    float v0 = 0.f, v1 = 0.f;
    if (t > 0) {
      // poll this wave's 128-wide k-chunk of (h_{t-1}+1) — FIRST vmem ops
      const float* ep = eb + (size_t)(t - 1) * H + w * 128;
      for (;;) {
        v0 = __hip_atomic_load(ep + l,      __ATOMIC_RELAXED, __HIP_MEMORY_SCOPE_AGENT);
        v1 = __hip_atomic_load(ep + 64 + l, __ATOMIC_RELAXED, __HIP_MEMORY_SCOPE_AGENT);
        if (!__any(!(v0 >= 1.0f && v1 >= 1.0f))) break;
      }
      // consume last step's prefetch (vmcnt already 0 here -> free);
      // memory clobber keeps the new prefetch issue below the poll.
      asm volatile("" :: "v"(kp0), "v"(kp1) : "memory");
      // wave-local LDS broadcast (same wave produces & consumes its region)
      shh[w * 128 + l]      = v0 - 1.0f;
      shh[w * 128 + 64 + l] = v1 - 1.0f;
      asm volatile("s_waitcnt lgkmcnt(0)" ::: "memory");
    } else {
      asm volatile("" ::: "memory");
    }

    // prefetch block: issued AFTER the poll, fills under the FMA phase and
    // stays in flight across the raw barrier.
    if (t + 1 < SEQ) {
      const float* pf = eb + (size_t)t * H + w * 128;
      kp0 = pf[l];
      kp1 = pf[64 + l];
      if (w == 0) xp_nxt = hb[(size_t)(t + 1) * H + n0 + l];
    }

    float partial = 0.f;
    if (t > 0) {
      float a0 = 0.f, a1 = 0.f, a2 = 0.f, a3 = 0.f;
#pragma unroll
      for (int i = 0; i < 16; ++i) {
        float4 hA = sh4[2 * i];
        float4 hB = sh4[2 * i + 1];
        a0 = fmaf(Wv[i][0], hA.x, a0);
        a1 = fmaf(Wv[i][1], hA.y, a1);
        a2 = fmaf(Wv[i][2], hA.z, a2);
        a3 = fmaf(Wv[i][3], hA.w, a3);
        a0 = fmaf(Wv[i][4], hB.x, a0);
        a1 = fmaf(Wv[i][5], hB.y, a1);
        a2 = fmaf(Wv[i][6], hB.z, a2);
        a3 = fmaf(Wv[i][7], hB.w, a3);
      }
      partial = (a0 + a1) + (a2 + a3);
    }

    sh_part[t & 1][w][l] = partial;
    // LDS-only barrier: do NOT drain vmcnt (prefetch stays in flight).
    asm volatile("s_waitcnt lgkmcnt(0)" ::: "memory");
    __builtin_amdgcn_s_barrier();
    asm volatile("" ::: "memory");

    if (w == 0) {
      float v = sh_part[t & 1][0][l] + sh_part[t & 1][1][l]
              + sh_part[t & 1][2][l] + sh_part[t & 1][3][l] + xp_cur + bn;
      float hv = fmaxf(v, 0.f);
      // publish h+1 (self-flagging) for peers
      __hip_atomic_store(&eb[(size_t)t * H + n0 + l], hv + 1.0f,
                         __ATOMIC_RELAXED, __HIP_MEMORY_SCOPE_AGENT);
      // clean h for the output / next GEMM
      hb[(size_t)t * H + n0 + l] = hv;
    }
    xp_cur = xp_nxt;
  }
}

// ---------------- in-place row softmax over 512 cols ----------------
__global__ __launch_bounds__(256) void softmax_k(float* __restrict__ Z) {
  __shared__ float smax[4];
  __shared__ float ssum[4];
  float* row = Z + (size_t)blockIdx.x * H;
  const int t = threadIdx.x;
  float2 v = *(float2*)&row[2 * t];
  float m = fmaxf(v.x, v.y);
#pragma unroll
  for (int o = 32; o > 0; o >>= 1) m = fmaxf(m, __shfl_xor(m, o, 64));
  const int wave = t >> 6, lane = t & 63;
  if (lane == 0) smax[wave] = m;
  __syncthreads();
  m = fmaxf(fmaxf(smax[0], smax[1]), fmaxf(smax[2], smax[3]));
  const float LOG2E = 1.44269504088896f;
  float ex = exp2f((v.x - m) * LOG2E);
  float ey = exp2f((v.y - m) * LOG2E);
  float s = ex + ey;
#pragma unroll
  for (int o = 32; o > 0; o >>= 1) s += __shfl_xor(s, o, 64);
  if (lane == 0) ssum[wave] = s;
  __syncthreads();
  float inv = 1.0f / (ssum[0] + ssum[1] + ssum[2] + ssum[3]);
  float2 r;
  r.x = ex * inv;
  r.y = ey * inv;
  *(float2*)&row[2 * t] = r;
}

extern "C" void kernel_launch(void* const* d_in, const int* in_sizes, int n_in,
                              void* d_out, int out_size, void* d_ws, size_t ws_size,
                              hipStream_t stream) {
  const float* x     = (const float*)d_in[0];
  const float* Whx_w = (const float*)d_in[1];
  const float* Whx_b = (const float*)d_in[2];
  const float* Whh_w = (const float*)d_in[3];
  const float* Whh_b = (const float*)d_in[4];
  const float* Woh_w = (const float*)d_in[5];
  const float* Woh_b = (const float*)d_in[6];

  float* y   = (float*)d_out;                           // output_arr; doubles as h+1 exchange
  float* hid = (float*)d_out + (size_t)BATCH * SEQ * H; // hidden_arr: xp then h
  float* Wt  = (float*)d_ws;                            // 1 MB

  const int M = BATCH * SEQ;  // 65536

  transpose_k<<<dim3(16, 16), 256, 0, stream>>>(Whh_w, Wt);
  gemm_bias_k<<<dim3(M / 128, H / 128), 256, 0, stream>>>(x, Whx_w, Whx_b, hid, M, H, DOBS);
  rnn_rec_k<<<BATCH * NSLICE, 256, 0, stream>>>(hid, y, Wt, Whh_b);
  gemm_bias_k<<<dim3(M / 128, H / 128), 256, 0, stream>>>(hid, Woh_w, Woh_b, y, M, H, H);
  softmax_k<<<M, 256, 0, stream>>>(y);
}